// Round 13
// baseline (179.603 us; speedup 1.0000x reference)
//
#include <hip/hip_runtime.h>
#include <hip/hip_bf16.h>

// B=2, T=2048, C=1024, H=16, HD=64. f32 I/O; bf16 MFMA internally, f32 accum.
//
//   0) prep (fused): x -> xb bf16 (seg0); w_qkv,w_out -> bf16 W^T[N][K]
//      via 64x64 transpose tiles, short8 coalesced writes (seg1/seg2).
//   1) gemm_glds<EPI=1,BN=128>: qkv proj. BK=64, XOR-swizzled LDS, glds16
//      staging, XCD-banded 1D grid (bid&7 owns an N-band; B-band L2-resident).
//      Q pre-scaled 0.125*log2e -> qk; K -> qk; V -> vt[B,H,64,T].
//   2) attn_mfma: flash attention (unchanged from R12 best: 4-wave blocks,
//      tile 4t+w, double-buffered K/V, 1 barrier/chunk, static exp2 softmax,
//      S^T operand order, XOR-swizzled aligned P).
//   3) gemm_glds<EPI=0,BN=64>: out proj, XCD-banded -> d_out f32

#define B_ 2
#define T_ 2048
#define C_ 1024
#define H_ 16
#define HD_ 64
#define M_ (B_ * T_)      // 4096
#define N3_ (3 * C_)      // 3072
#define QK2_ 2048
#define QSCALE 0.18033688f   // 0.125 * log2(e)

typedef __attribute__((ext_vector_type(8))) short short8;
typedef __attribute__((ext_vector_type(4))) short short4v;
typedef __attribute__((ext_vector_type(4))) float floatx4;

__device__ __forceinline__ unsigned short f2b(float f) {
    __hip_bfloat16 h = __float2bfloat16(f);
    return *reinterpret_cast<unsigned short*>(&h);
}

__device__ __forceinline__ void glds16(const void* g, void* l) {
    __builtin_amdgcn_global_load_lds(
        (const __attribute__((address_space(1))) void*)g,
        (__attribute__((address_space(3))) void*)l, 16, 0, 0);
}

// ---------------------------------------------------------------------------
// Fused prep. seg0 (4096 blocks): x f32->bf16. seg1 (1536): w_qkv [1024][3072]
// -> wt1 [3072][1024], 64(k) x 32(n) tiles. seg2 (512): w_out -> wt2.
// Write phase: each lane stores a contiguous short8 (16 B) -> 128 B per
// 8 lanes, fully coalesced (old 32x32 version wrote 2 B/lane).
// ---------------------------------------------------------------------------
__global__ __launch_bounds__(256) void prep(
    const float* __restrict__ x, const float* __restrict__ w_qkv,
    const float* __restrict__ w_out, unsigned short* __restrict__ xb,
    unsigned short* __restrict__ wt1, unsigned short* __restrict__ wt2) {
    __shared__ float t[64][33];
    const int bi = blockIdx.x;
    const int tid = threadIdx.x;
    if (bi < 4096) {
        int i = (bi * 256 + tid) * 4;
        float4 v = *reinterpret_cast<const float4*>(x + i);
        short4v s;
        s[0] = (short)f2b(v.x); s[1] = (short)f2b(v.y);
        s[2] = (short)f2b(v.z); s[3] = (short)f2b(v.w);
        *reinterpret_cast<short4v*>(xb + i) = s;
        return;
    }
    const float* src; unsigned short* dst; int n0, k0, N;
    if (bi < 4096 + 1536) {
        int u = bi - 4096;
        src = w_qkv; dst = wt1; N = N3_;
        k0 = (u & 15) * 64; n0 = (u >> 4) * 32;
    } else {
        int u = bi - (4096 + 1536);
        src = w_out; dst = wt2; N = C_;
        k0 = (u & 15) * 64; n0 = (u >> 4) * 32;
    }
    const int tx = tid & 31, ty = tid >> 5;        // read: 32 n x 8 k-rows
#pragma unroll
    for (int i = 0; i < 8; i++)
        t[ty + i * 8][tx] = src[(size_t)(k0 + ty + i * 8) * N + n0 + tx];
    __syncthreads();
    const int row = tid >> 3;                      // write: n-row 0..31
    const int kp  = (tid & 7) * 8;                 // k-chunk of 8
    short8 o;
#pragma unroll
    for (int j = 0; j < 8; j++) o[j] = (short)f2b(t[kp + j][row]);
    *reinterpret_cast<short8*>(&dst[(size_t)(n0 + row) * C_ + k0 + kp]) = o;
}

// ---------------------------------------------------------------------------
// GEMM: C[M,N] = A[M,K] @ Bt^T[N,K] + bias[N]. A,Bt bf16. Tile 128 x BN,
// BK=64, 4 waves 2x2. LDS rows 64 shorts, XOR chunk swizzle (conflict-free
// b128 frag reads); glds16 staging carries the swizzle in the source column.
// 1D grid, XCD-banded: xcd = bid&7 owns N-tiles [xcd*NT/8, (xcd+1)*NT/8);
// within an XCD, consecutive blocks share the A-tile (L2 reuse).
// ---------------------------------------------------------------------------
template<int EPI, int BN>
__global__ __launch_bounds__(256) void gemm_glds(
    const unsigned short* __restrict__ A, const unsigned short* __restrict__ Bt,
    const float* __restrict__ bias, void* __restrict__ Cp,
    unsigned short* __restrict__ vtp, int M, int N, int K) {
    constexpr int NI = BN / 32;
    __shared__ __align__(16) unsigned short Al[128 * 64];
    __shared__ __align__(16) unsigned short Bl[BN * 64];

    const int tid  = threadIdx.x;
    const int lane = tid & 63;
    const int w    = tid >> 6;
    const int c16  = lane & 15;
    const int quad = lane >> 4;
    // XCD-banded block mapping (bid%8 -> XCD heuristic; worst case neutral)
    const int NT  = N / BN;
    const int pe  = NT >> 3;                  // N-tiles per XCD
    const int xcd = blockIdx.x & 7;
    const int ii  = blockIdx.x >> 3;
    const int n0  = (xcd * pe + ii % pe) * BN;
    const int m0  = (ii / pe) * 128;
    const int wm = (w >> 1) * 64;
    const int wn = (w & 1) * (BN / 2);

    floatx4 acc[4][NI] = {};

    const int srow = lane >> 3;
    const int sch  = ((lane & 7) ^ srow) * 8;
    const unsigned short* ag = A + (size_t)(m0 + w * 32 + srow) * K + sch;
    const unsigned short* bg = Bt + (size_t)(n0 + w * (BN / 4) + srow) * K + sch;

    const int s7 = c16 & 7;

    for (int k0 = 0; k0 < K; k0 += 64) {
        __syncthreads();
#pragma unroll
        for (int i = 0; i < 4; i++)
            glds16(ag + k0 + (size_t)(i * 8) * K, &Al[(w * 32 + i * 8) * 64]);
#pragma unroll
        for (int i = 0; i < BN / 32; i++)
            glds16(bg + k0 + (size_t)(i * 8) * K,
                   &Bl[(w * (BN / 4) + i * 8) * 64]);
        __syncthreads();

        short8 af[4][2], bf[NI][2];
#pragma unroll
        for (int im = 0; im < 4; im++)
#pragma unroll
            for (int kk = 0; kk < 2; kk++)
                af[im][kk] = *reinterpret_cast<const short8*>(
                    &Al[(wm + im * 16 + c16) * 64 + ((kk * 4 + quad) ^ s7) * 8]);
#pragma unroll
        for (int in = 0; in < NI; in++)
#pragma unroll
            for (int kk = 0; kk < 2; kk++)
                bf[in][kk] = *reinterpret_cast<const short8*>(
                    &Bl[(wn + in * 16 + c16) * 64 + ((kk * 4 + quad) ^ s7) * 8]);
#pragma unroll
        for (int im = 0; im < 4; im++)
#pragma unroll
            for (int in = 0; in < NI; in++)
#pragma unroll
                for (int kk = 0; kk < 2; kk++)
                    acc[im][in] = __builtin_amdgcn_mfma_f32_16x16x32_bf16(
                        af[im][kk], bf[in][kk], acc[im][in], 0, 0, 0);
    }

    const int ncol = n0 + wn;
    float bv[NI];
#pragma unroll
    for (int in = 0; in < NI; in++) bv[in] = bias[ncol + in * 16 + c16];

    if (EPI == 0) {
        float* C = (float*)Cp;
#pragma unroll
        for (int im = 0; im < 4; im++)
#pragma unroll
            for (int r = 0; r < 4; r++) {
                int row = m0 + wm + im * 16 + quad * 4 + r;
#pragma unroll
                for (int in = 0; in < NI; in++)
                    C[(size_t)row * N + ncol + in * 16 + c16] =
                        acc[im][in][r] + bv[in];
            }
    } else {
        if (ncol < 2 * C_) {     // Q or K -> qk (wave-uniform branch)
            const float fac = (ncol < C_) ? QSCALE : 1.0f;
            unsigned short* qkp = (unsigned short*)Cp;
#pragma unroll
            for (int im = 0; im < 4; im++)
#pragma unroll
                for (int r = 0; r < 4; r++) {
                    int row = m0 + wm + im * 16 + quad * 4 + r;
#pragma unroll
                    for (int in = 0; in < NI; in++)
                        qkp[(size_t)row * QK2_ + ncol + in * 16 + c16] =
                            f2b((acc[im][in][r] + bv[in]) * fac);
                }
        } else {                 // V -> vt[B,H,64,T]
#pragma unroll
            for (int im = 0; im < 4; im++) {
                int row0 = m0 + wm + im * 16 + quad * 4;
                int b  = row0 >> 11;
                int t0 = row0 & (T_ - 1);
#pragma unroll
                for (int in = 0; in < NI; in++) {
                    int dfull = ncol - 2 * C_ + in * 16 + c16;  // h*64+d
                    short4v sv;
#pragma unroll
                    for (int r = 0; r < 4; r++)
                        sv[r] = (short)f2b(acc[im][in][r] + bv[in]);
                    *reinterpret_cast<short4v*>(
                        &vtp[(((size_t)(b << 10) + dfull) << 11) + t0]) = sv;
                }
            }
        }
    }
}

// ---------------------------------------------------------------------------
// One 16-row Q-tile x 64-key chunk, S^T form (K-frag as A operand): lane
// (c16,quad) holds S[qrow=row0+c16][key=kb+nt*16+quad*4+r].
// P buffer: 64-short rows, XOR chunk swizzle -> 16B-aligned b128 reads,
// conflict-free. MASKED only on the final chunk. Kl/Vl XOR-swizzled.
// ---------------------------------------------------------------------------
template<bool MASKED>
__device__ __forceinline__ void attn_tile(
    short8 af0, short8 af1,
    const unsigned short* __restrict__ Kb,
    const unsigned short* __restrict__ Vb,
    unsigned short* __restrict__ pw,
    floatx4 O[4], float& l,
    int row0, int kb, int c16, int quad) {
    const floatx4 z = {0.f, 0.f, 0.f, 0.f};
    const int sx  = c16 & 7;
    const int ch0 = (quad ^ sx) * 8;
    const int ch1 = ((quad + 4) ^ sx) * 8;
    floatx4 s[4];
#pragma unroll
    for (int nt = 0; nt < 4; nt++) {
        const int rb = (nt * 16 + c16) * 64;
        short8 k0 = *reinterpret_cast<const short8*>(&Kb[rb + ch0]);
        short8 k1 = *reinterpret_cast<const short8*>(&Kb[rb + ch1]);
        floatx4 t = __builtin_amdgcn_mfma_f32_16x16x32_bf16(k0, af0, z, 0, 0, 0);
        s[nt] = __builtin_amdgcn_mfma_f32_16x16x32_bf16(k1, af1, t, 0, 0, 0);
    }
    const int qrow = row0 + c16;
#pragma unroll
    for (int nt = 0; nt < 4; nt++) {
        short4v p4;
#pragma unroll
        for (int r = 0; r < 4; r++) {
            float p;
            if (MASKED) {
                int key = kb + nt * 16 + quad * 4 + r;
                p = (key <= qrow) ? exp2f(s[nt][r]) : 0.f;
            } else {
                p = exp2f(s[nt][r]);
            }
            l += p;
            p4[r] = (short)f2b(p);
        }
        const int pst = ((2 * nt + (quad >> 1)) ^ sx) * 8 + (quad & 1) * 4;
        *reinterpret_cast<short4v*>(&pw[c16 * 64 + pst]) = p4;
    }
    short8 pf0 = *reinterpret_cast<const short8*>(&pw[c16 * 64 + ch0]);
    short8 pf1 = *reinterpret_cast<const short8*>(&pw[c16 * 64 + ch1]);
#pragma unroll
    for (int nt = 0; nt < 4; nt++) {
        const int rb = (nt * 16 + c16) * 64;
        short8 v0 = *reinterpret_cast<const short8*>(&Vb[rb + ch0]);
        short8 v1 = *reinterpret_cast<const short8*>(&Vb[rb + ch1]);
        floatx4 t = __builtin_amdgcn_mfma_f32_16x16x32_bf16(pf0, v0, O[nt], 0, 0, 0);
        O[nt] = __builtin_amdgcn_mfma_f32_16x16x32_bf16(pf1, v1, t, 0, 0, 0);
    }
}

// ---------------------------------------------------------------------------
// Flash attention (R12 structure, unchanged). Block = 256 thr = 4 waves;
// wave w owns tile 4t+w; nch = t+1 uniform. Grid 1024, LPT. Double-buffered
// K/V, 1 barrier/chunk. LDS 40 KB -> 4 blocks/CU.
// ---------------------------------------------------------------------------
__global__ __launch_bounds__(256) void attn_mfma(
    const unsigned short* __restrict__ qk,
    const unsigned short* __restrict__ vt,
    unsigned short* __restrict__ y) {
    __shared__ __align__(16) unsigned short Kl[2][64 * 64];
    __shared__ __align__(16) unsigned short Vl[2][64 * 64];
    __shared__ __align__(16) unsigned short Pl[4 * 16 * 64];

    const int tid  = threadIdx.x;
    const int lane = tid & 63;
    const int w    = tid >> 6;
    const int c16  = lane & 15;
    const int quad = lane >> 4;
    const int bh = blockIdx.x & 31;
    const int t  = 31 - (blockIdx.x >> 5);   // longest-first
    const int b  = bh >> 4;
    const int h  = bh & 15;
    const int row0 = (4 * t + w) * 16;
    const int nch  = t + 1;

    const unsigned short* qrow = qk + (size_t)b * T_ * QK2_ + h * HD_;
    const unsigned short* krow = qrow + C_;
    const unsigned short* vrow = vt + ((size_t)bh << 6) * T_;

    short8 af0 = *reinterpret_cast<const short8*>(
        qrow + (size_t)(row0 + c16) * QK2_ + quad * 8);
    short8 af1 = *reinterpret_cast<const short8*>(
        qrow + (size_t)(row0 + c16) * QK2_ + 32 + quad * 8);

    floatx4 O[4] = {};
    float l = 0.f;
    unsigned short* pw = &Pl[w * 16 * 64];

    const int r8 = lane >> 3;
    const int sw = ((lane & 7) ^ r8) * 8;

    // stage chunk 0 into buffer 0
#pragma unroll
    for (int i = 0; i < 2; i++) {
        const int row = w * 16 + i * 8 + r8;
        glds16(krow + (size_t)row * QK2_ + sw, &Kl[0][(w * 16 + i * 8) * 64]);
        glds16(vrow + (size_t)row * T_ + sw,   &Vl[0][(w * 16 + i * 8) * 64]);
    }

    for (int c = 0; c < nch; c++) {
        __syncthreads();       // chunk c staged; buf (c+1)&1 reads (iter c-1) done
        if (c + 1 < nch) {     // prefetch chunk c+1 into the other buffer
            const int kb2 = (c + 1) * 64;
            const int nb = (c + 1) & 1;
#pragma unroll
            for (int i = 0; i < 2; i++) {
                const int row = w * 16 + i * 8 + r8;
                glds16(krow + (size_t)(kb2 + row) * QK2_ + sw,
                       &Kl[nb][(w * 16 + i * 8) * 64]);
                glds16(vrow + (size_t)row * T_ + kb2 + sw,
                       &Vl[nb][(w * 16 + i * 8) * 64]);
            }
        }
        const int kb = c * 64;
        if (c + 1 < nch)
            attn_tile<false>(af0, af1, Kl[c & 1], Vl[c & 1], pw, O, l,
                             row0, kb, c16, quad);
        else
            attn_tile<true>(af0, af1, Kl[c & 1], Vl[c & 1], pw, O, l,
                            row0, kb, c16, quad);
    }

    // l per-lane -> per-row (qrow = row0 + c16, keys split across quads)
    l += __shfl_xor(l, 16);
    l += __shfl_xor(l, 32);
    float lr[4];
#pragma unroll
    for (int r = 0; r < 4; r++)
        lr[r] = __shfl(l, quad * 4 + r);

#pragma unroll
    for (int nt = 0; nt < 4; nt++)
#pragma unroll
        for (int r = 0; r < 4; r++) {
            float val = O[nt][r] / fmaxf(lr[r], 1e-30f);
            y[((size_t)b * T_ + row0 + quad * 4 + r) * C_ + h * HD_ + nt * 16 + c16] =
                f2b(val);
        }
}

extern "C" void kernel_launch(void* const* d_in, const int* in_sizes, int n_in,
                              void* d_out, int out_size, void* d_ws, size_t ws_size,
                              hipStream_t stream) {
    const float* x     = (const float*)d_in[0];
    const float* w_qkv = (const float*)d_in[1];
    const float* b_qkv = (const float*)d_in[2];
    const float* w_out = (const float*)d_in[3];
    const float* b_out = (const float*)d_in[4];
    float* out = (float*)d_out;

    unsigned short* qkb = (unsigned short*)d_ws;                 // [4096][2048]
    unsigned short* vtb = qkb + (size_t)M_ * QK2_;               // [B,H,64,T]
    unsigned short* yb  = vtb + (size_t)B_ * H_ * HD_ * T_;      // [4096][1024]
    unsigned short* wt1 = yb + (size_t)M_ * C_;                  // [3072][1024]
    unsigned short* wt2 = wt1 + (size_t)N3_ * C_;                // [1024][1024]
    unsigned short* xb  = wt2 + (size_t)C_ * C_;                 // [4096][1024]

    prep<<<4096 + 1536 + 512, 256, 0, stream>>>(x, w_qkv, w_out, xb, wt1, wt2);

    gemm_glds<1, 128><<<(N3_ / 128) * (M_ / 128), 256, 0, stream>>>(
        xb, wt1, b_qkv, qkb, vtb, M_, N3_, C_);

    attn_mfma<<<B_ * H_ * 32, 256, 0, stream>>>(qkb, vtb, yb);

    gemm_glds<0, 64><<<(C_ / 64) * (M_ / 128), 256, 0, stream>>>(
        yb, wt2, b_out, out, nullptr, M_, C_, C_);
}

// Round 14
// 175.489 us; speedup vs baseline: 1.0234x; 1.0234x over previous
//
#include <hip/hip_runtime.h>
#include <hip/hip_bf16.h>

// B=2, T=2048, C=1024, H=16, HD=64. f32 I/O; bf16 MFMA internally, f32 accum.
//
//   0) prep (fused): x -> xb bf16; w_qkv,w_out -> bf16 W^T[N][K]
//   1) gemm_glds<EPI=1,BN=128>: qkv proj (BK=64, XOR-swizzled LDS, glds16).
//      Q pre-scaled 0.125*log2e -> qk; K -> qk; V -> vt[B,H,64,T].
//   2) attn_mfma: flash attention, static exp2 softmax (linear in chunks ->
//      exact split-chunk parallelism). 512-thr / 8-wave blocks: wave w owns
//      tile 4t+(w&3), parity w>>2 computes chunks c with c&1==parity; pair
//      shares one P buffer (alternating iterations, barrier-ordered); merge
//      O/l by addition through the dead K/V LDS at the end. 32 waves/CU.
//   3) gemm_glds<EPI=0,BN=64>: out proj -> d_out f32

#define B_ 2
#define T_ 2048
#define C_ 1024
#define H_ 16
#define HD_ 64
#define M_ (B_ * T_)      // 4096
#define N3_ (3 * C_)      // 3072
#define QK2_ 2048
#define QSCALE 0.18033688f   // 0.125 * log2(e)

typedef __attribute__((ext_vector_type(8))) short short8;
typedef __attribute__((ext_vector_type(4))) short short4v;
typedef __attribute__((ext_vector_type(4))) float floatx4;

__device__ __forceinline__ unsigned short f2b(float f) {
    __hip_bfloat16 h = __float2bfloat16(f);
    return *reinterpret_cast<unsigned short*>(&h);
}

__device__ __forceinline__ void glds16(const void* g, void* l) {
    __builtin_amdgcn_global_load_lds(
        (const __attribute__((address_space(1))) void*)g,
        (__attribute__((address_space(3))) void*)l, 16, 0, 0);
}

// ---------------------------------------------------------------------------
// Fused prep. seg0 (4096 blocks): x f32->bf16. seg1 (1536): w_qkv -> wt1
// [3072][1024] via 64(k)x32(n) tiles, short8 coalesced writes. seg2 (512):
// w_out -> wt2.
// ---------------------------------------------------------------------------
__global__ __launch_bounds__(256) void prep(
    const float* __restrict__ x, const float* __restrict__ w_qkv,
    const float* __restrict__ w_out, unsigned short* __restrict__ xb,
    unsigned short* __restrict__ wt1, unsigned short* __restrict__ wt2) {
    __shared__ float t[64][33];
    const int bi = blockIdx.x;
    const int tid = threadIdx.x;
    if (bi < 4096) {
        int i = (bi * 256 + tid) * 4;
        float4 v = *reinterpret_cast<const float4*>(x + i);
        short4v s;
        s[0] = (short)f2b(v.x); s[1] = (short)f2b(v.y);
        s[2] = (short)f2b(v.z); s[3] = (short)f2b(v.w);
        *reinterpret_cast<short4v*>(xb + i) = s;
        return;
    }
    const float* src; unsigned short* dst; int n0, k0, N;
    if (bi < 4096 + 1536) {
        int u = bi - 4096;
        src = w_qkv; dst = wt1; N = N3_;
        k0 = (u & 15) * 64; n0 = (u >> 4) * 32;
    } else {
        int u = bi - (4096 + 1536);
        src = w_out; dst = wt2; N = C_;
        k0 = (u & 15) * 64; n0 = (u >> 4) * 32;
    }
    const int tx = tid & 31, ty = tid >> 5;
#pragma unroll
    for (int i = 0; i < 8; i++)
        t[ty + i * 8][tx] = src[(size_t)(k0 + ty + i * 8) * N + n0 + tx];
    __syncthreads();
    const int row = tid >> 3;
    const int kp  = (tid & 7) * 8;
    short8 o;
#pragma unroll
    for (int j = 0; j < 8; j++) o[j] = (short)f2b(t[kp + j][row]);
    *reinterpret_cast<short8*>(&dst[(size_t)(n0 + row) * C_ + k0 + kp]) = o;
}

// ---------------------------------------------------------------------------
// GEMM: C[M,N] = A[M,K] @ Bt^T[N,K] + bias[N]. A,Bt bf16. Tile 128 x BN,
// BK=64, 4 waves 2x2. LDS rows 64 shorts, XOR chunk swizzle; glds16 staging.
// 1D grid, XCD-banded (neutral-at-worst heuristic).
// ---------------------------------------------------------------------------
template<int EPI, int BN>
__global__ __launch_bounds__(256) void gemm_glds(
    const unsigned short* __restrict__ A, const unsigned short* __restrict__ Bt,
    const float* __restrict__ bias, void* __restrict__ Cp,
    unsigned short* __restrict__ vtp, int M, int N, int K) {
    constexpr int NI = BN / 32;
    __shared__ __align__(16) unsigned short Al[128 * 64];
    __shared__ __align__(16) unsigned short Bl[BN * 64];

    const int tid  = threadIdx.x;
    const int lane = tid & 63;
    const int w    = tid >> 6;
    const int c16  = lane & 15;
    const int quad = lane >> 4;
    const int NT  = N / BN;
    const int pe  = NT >> 3;
    const int xcd = blockIdx.x & 7;
    const int ii  = blockIdx.x >> 3;
    const int n0  = (xcd * pe + ii % pe) * BN;
    const int m0  = (ii / pe) * 128;
    const int wm = (w >> 1) * 64;
    const int wn = (w & 1) * (BN / 2);

    floatx4 acc[4][NI] = {};

    const int srow = lane >> 3;
    const int sch  = ((lane & 7) ^ srow) * 8;
    const unsigned short* ag = A + (size_t)(m0 + w * 32 + srow) * K + sch;
    const unsigned short* bg = Bt + (size_t)(n0 + w * (BN / 4) + srow) * K + sch;

    const int s7 = c16 & 7;

    for (int k0 = 0; k0 < K; k0 += 64) {
        __syncthreads();
#pragma unroll
        for (int i = 0; i < 4; i++)
            glds16(ag + k0 + (size_t)(i * 8) * K, &Al[(w * 32 + i * 8) * 64]);
#pragma unroll
        for (int i = 0; i < BN / 32; i++)
            glds16(bg + k0 + (size_t)(i * 8) * K,
                   &Bl[(w * (BN / 4) + i * 8) * 64]);
        __syncthreads();

        short8 af[4][2], bf[NI][2];
#pragma unroll
        for (int im = 0; im < 4; im++)
#pragma unroll
            for (int kk = 0; kk < 2; kk++)
                af[im][kk] = *reinterpret_cast<const short8*>(
                    &Al[(wm + im * 16 + c16) * 64 + ((kk * 4 + quad) ^ s7) * 8]);
#pragma unroll
        for (int in = 0; in < NI; in++)
#pragma unroll
            for (int kk = 0; kk < 2; kk++)
                bf[in][kk] = *reinterpret_cast<const short8*>(
                    &Bl[(wn + in * 16 + c16) * 64 + ((kk * 4 + quad) ^ s7) * 8]);
#pragma unroll
        for (int im = 0; im < 4; im++)
#pragma unroll
            for (int in = 0; in < NI; in++)
#pragma unroll
                for (int kk = 0; kk < 2; kk++)
                    acc[im][in] = __builtin_amdgcn_mfma_f32_16x16x32_bf16(
                        af[im][kk], bf[in][kk], acc[im][in], 0, 0, 0);
    }

    const int ncol = n0 + wn;
    float bv[NI];
#pragma unroll
    for (int in = 0; in < NI; in++) bv[in] = bias[ncol + in * 16 + c16];

    if (EPI == 0) {
        float* C = (float*)Cp;
#pragma unroll
        for (int im = 0; im < 4; im++)
#pragma unroll
            for (int r = 0; r < 4; r++) {
                int row = m0 + wm + im * 16 + quad * 4 + r;
#pragma unroll
                for (int in = 0; in < NI; in++)
                    C[(size_t)row * N + ncol + in * 16 + c16] =
                        acc[im][in][r] + bv[in];
            }
    } else {
        if (ncol < 2 * C_) {
            const float fac = (ncol < C_) ? QSCALE : 1.0f;
            unsigned short* qkp = (unsigned short*)Cp;
#pragma unroll
            for (int im = 0; im < 4; im++)
#pragma unroll
                for (int r = 0; r < 4; r++) {
                    int row = m0 + wm + im * 16 + quad * 4 + r;
#pragma unroll
                    for (int in = 0; in < NI; in++)
                        qkp[(size_t)row * QK2_ + ncol + in * 16 + c16] =
                            f2b((acc[im][in][r] + bv[in]) * fac);
                }
        } else {                 // V -> vt[B,H,64,T]
#pragma unroll
            for (int im = 0; im < 4; im++) {
                int row0 = m0 + wm + im * 16 + quad * 4;
                int b  = row0 >> 11;
                int t0 = row0 & (T_ - 1);
#pragma unroll
                for (int in = 0; in < NI; in++) {
                    int dfull = ncol - 2 * C_ + in * 16 + c16;
                    short4v sv;
#pragma unroll
                    for (int r = 0; r < 4; r++)
                        sv[r] = (short)f2b(acc[im][in][r] + bv[in]);
                    *reinterpret_cast<short4v*>(
                        &vtp[(((size_t)(b << 10) + dfull) << 11) + t0]) = sv;
                }
            }
        }
    }
}

// ---------------------------------------------------------------------------
// One 16-row Q-tile x 64-key chunk, S^T form. P buffer: 64-short rows, XOR
// chunk swizzle (16B-aligned, conflict-free). MASKED only on final chunk.
// ---------------------------------------------------------------------------
template<bool MASKED>
__device__ __forceinline__ void attn_tile(
    short8 af0, short8 af1,
    const unsigned short* __restrict__ Kb,
    const unsigned short* __restrict__ Vb,
    unsigned short* __restrict__ pw,
    floatx4 O[4], float& l,
    int row0, int kb, int c16, int quad) {
    const floatx4 z = {0.f, 0.f, 0.f, 0.f};
    const int sx  = c16 & 7;
    const int ch0 = (quad ^ sx) * 8;
    const int ch1 = ((quad + 4) ^ sx) * 8;
    floatx4 s[4];
#pragma unroll
    for (int nt = 0; nt < 4; nt++) {
        const int rb = (nt * 16 + c16) * 64;
        short8 k0 = *reinterpret_cast<const short8*>(&Kb[rb + ch0]);
        short8 k1 = *reinterpret_cast<const short8*>(&Kb[rb + ch1]);
        floatx4 t = __builtin_amdgcn_mfma_f32_16x16x32_bf16(k0, af0, z, 0, 0, 0);
        s[nt] = __builtin_amdgcn_mfma_f32_16x16x32_bf16(k1, af1, t, 0, 0, 0);
    }
    const int qrow = row0 + c16;
#pragma unroll
    for (int nt = 0; nt < 4; nt++) {
        short4v p4;
#pragma unroll
        for (int r = 0; r < 4; r++) {
            float p;
            if (MASKED) {
                int key = kb + nt * 16 + quad * 4 + r;
                p = (key <= qrow) ? exp2f(s[nt][r]) : 0.f;
            } else {
                p = exp2f(s[nt][r]);
            }
            l += p;
            p4[r] = (short)f2b(p);
        }
        const int pst = ((2 * nt + (quad >> 1)) ^ sx) * 8 + (quad & 1) * 4;
        *reinterpret_cast<short4v*>(&pw[c16 * 64 + pst]) = p4;
    }
    short8 pf0 = *reinterpret_cast<const short8*>(&pw[c16 * 64 + ch0]);
    short8 pf1 = *reinterpret_cast<const short8*>(&pw[c16 * 64 + ch1]);
#pragma unroll
    for (int nt = 0; nt < 4; nt++) {
        const int rb = (nt * 16 + c16) * 64;
        short8 v0 = *reinterpret_cast<const short8*>(&Vb[rb + ch0]);
        short8 v1 = *reinterpret_cast<const short8*>(&Vb[rb + ch1]);
        floatx4 t = __builtin_amdgcn_mfma_f32_16x16x32_bf16(pf0, v0, O[nt], 0, 0, 0);
        O[nt] = __builtin_amdgcn_mfma_f32_16x16x32_bf16(pf1, v1, t, 0, 0, 0);
    }
}

// ---------------------------------------------------------------------------
// Flash attention, split-chunk. Block = 512 thr = 8 waves; wave w owns tile
// 4t+(w&3); parity par=w>>2 computes chunks c with c&1==par (static softmax
// is chunk-linear -> exact merge by addition). Pair shares one P buffer
// (alternating iterations, barrier-ordered). Double-buffered K/V staged by
// all 8 waves (8 rows each), 1 barrier/chunk. Merge through dead K/V LDS.
// LDS 40 KB, VGPR ~52 -> 4 blocks/CU = 32 waves/CU. Grid 1024, LPT.
// ---------------------------------------------------------------------------
__global__ __launch_bounds__(512) void attn_mfma(
    const unsigned short* __restrict__ qk,
    const unsigned short* __restrict__ vt,
    unsigned short* __restrict__ y) {
    __shared__ __align__(16) unsigned short Kl[2][64 * 64];
    __shared__ __align__(16) unsigned short Vl[2][64 * 64];
    __shared__ __align__(16) unsigned short Pl[4 * 16 * 64];

    const int tid  = threadIdx.x;
    const int lane = tid & 63;
    const int w    = tid >> 6;          // 0..7
    const int wq   = w & 3;             // tile slot
    const int par  = w >> 2;            // chunk parity
    const int c16  = lane & 15;
    const int quad = lane >> 4;
    const int bh = blockIdx.x & 31;
    const int t  = 31 - (blockIdx.x >> 5);   // longest-first
    const int b  = bh >> 4;
    const int h  = bh & 15;
    const int row0 = (4 * t + wq) * 16;
    const int nch  = t + 1;

    const unsigned short* qrow = qk + (size_t)b * T_ * QK2_ + h * HD_;
    const unsigned short* krow = qrow + C_;
    const unsigned short* vrow = vt + ((size_t)bh << 6) * T_;

    short8 af0 = *reinterpret_cast<const short8*>(
        qrow + (size_t)(row0 + c16) * QK2_ + quad * 8);
    short8 af1 = *reinterpret_cast<const short8*>(
        qrow + (size_t)(row0 + c16) * QK2_ + 32 + quad * 8);

    floatx4 O[4] = {};
    float l = 0.f;
    unsigned short* pw = &Pl[wq * 16 * 64];    // shared by the parity pair

    const int r8 = lane >> 3;
    const int sw = ((lane & 7) ^ r8) * 8;
    const int srow = w * 8 + r8;               // this wave's staging row 0..63

    // stage chunk 0 into buffer 0 (each wave: 1 K row-group + 1 V row-group)
    glds16(krow + (size_t)srow * QK2_ + sw, &Kl[0][(w * 8) * 64]);
    glds16(vrow + (size_t)srow * T_ + sw,   &Vl[0][(w * 8) * 64]);

    for (int c = 0; c < nch; c++) {
        __syncthreads();       // chunk c staged; prev buf reads done
        if (c + 1 < nch) {     // prefetch chunk c+1 into the other buffer
            const int kb2 = (c + 1) * 64;
            const int nb = (c + 1) & 1;
            glds16(krow + (size_t)(kb2 + srow) * QK2_ + sw, &Kl[nb][(w * 8) * 64]);
            glds16(vrow + (size_t)srow * T_ + kb2 + sw,     &Vl[nb][(w * 8) * 64]);
        }
        if ((c & 1) == par) {  // wave-uniform: this parity's chunk
            const int kb = c * 64;
            if (c + 1 < nch)
                attn_tile<false>(af0, af1, Kl[c & 1], Vl[c & 1], pw, O, l,
                                 row0, kb, c16, quad);
            else
                attn_tile<true>(af0, af1, Kl[c & 1], Vl[c & 1], pw, O, l,
                                row0, kb, c16, quad);
        }
    }

    // merge the parity pair: odd waves park O (16 f32/lane) + l in the dead
    // K/V buffers; even waves add.
    __syncthreads();
    float* Kf = (float*)&Kl[0][0];     // 4096 floats = 4 tiles x 1024
    float* Vf = (float*)&Vl[0][0];
    if (par) {
#pragma unroll
        for (int nt = 0; nt < 4; nt++)
            *reinterpret_cast<floatx4*>(&Kf[wq * 1024 + lane * 16 + nt * 4]) = O[nt];
        Vf[wq * 64 + lane] = l;
    }
    __syncthreads();
    if (par == 0) {
#pragma unroll
        for (int nt = 0; nt < 4; nt++)
            O[nt] += *reinterpret_cast<const floatx4*>(
                &Kf[wq * 1024 + lane * 16 + nt * 4]);
        l += Vf[wq * 64 + lane];

        // l per-lane -> per-row (qrow = row0 + c16, keys split across quads)
        l += __shfl_xor(l, 16);
        l += __shfl_xor(l, 32);
        float lr[4];
#pragma unroll
        for (int r = 0; r < 4; r++)
            lr[r] = __shfl(l, quad * 4 + r);

#pragma unroll
        for (int nt = 0; nt < 4; nt++)
#pragma unroll
            for (int r = 0; r < 4; r++) {
                float val = O[nt][r] / fmaxf(lr[r], 1e-30f);
                y[((size_t)b * T_ + row0 + quad * 4 + r) * C_ + h * HD_ +
                  nt * 16 + c16] = f2b(val);
            }
    }
}

extern "C" void kernel_launch(void* const* d_in, const int* in_sizes, int n_in,
                              void* d_out, int out_size, void* d_ws, size_t ws_size,
                              hipStream_t stream) {
    const float* x     = (const float*)d_in[0];
    const float* w_qkv = (const float*)d_in[1];
    const float* b_qkv = (const float*)d_in[2];
    const float* w_out = (const float*)d_in[3];
    const float* b_out = (const float*)d_in[4];
    float* out = (float*)d_out;

    unsigned short* qkb = (unsigned short*)d_ws;                 // [4096][2048]
    unsigned short* vtb = qkb + (size_t)M_ * QK2_;               // [B,H,64,T]
    unsigned short* yb  = vtb + (size_t)B_ * H_ * HD_ * T_;      // [4096][1024]
    unsigned short* wt1 = yb + (size_t)M_ * C_;                  // [3072][1024]
    unsigned short* wt2 = wt1 + (size_t)N3_ * C_;                // [1024][1024]
    unsigned short* xb  = wt2 + (size_t)C_ * C_;                 // [4096][1024]

    prep<<<4096 + 1536 + 512, 256, 0, stream>>>(x, w_qkv, w_out, xb, wt1, wt2);

    gemm_glds<1, 128><<<(N3_ / 128) * (M_ / 128), 256, 0, stream>>>(
        xb, wt1, b_qkv, qkb, vtb, M_, N3_, C_);

    attn_mfma<<<B_ * H_ * 32, 512, 0, stream>>>(qkb, vtb, yb);

    gemm_glds<0, 64><<<(C_ / 64) * (M_ / 128), 256, 0, stream>>>(
        yb, wt2, b_out, out, nullptr, M_, C_, C_);
}